// Round 1
// baseline (3075.817 us; speedup 1.0000x reference)
//
#include <hip/hip_runtime.h>
#include <math.h>

#define NN 50000
#define NE 800000
#define DD 128
#define DOUT 40
#define BN_EPS_F 1e-5f

// ---------------- copy (agg init: agg = x) ----------------
__global__ void k_copy(const float4* __restrict__ s, float4* __restrict__ d, int n4) {
  int i = blockIdx.x * 256 + threadIdx.x;
  if (i < n4) d[i] = s[i];
}

// ---------------- scatter-add: agg[dst] += x[src] ----------------
__global__ void k_scatter(const float4* __restrict__ x, const int* __restrict__ srcI,
                          const int* __restrict__ dstI, float* __restrict__ agg) {
  int tid = blockIdx.x * 256 + threadIdx.x;
  int e = tid >> 5;
  if (e >= NE) return;
  int c = tid & 31;
  int s = srcI[e], t = dstI[e];
  float4 v = x[s * 32 + c];
  float* p = agg + t * DD + c * 4;
  atomicAdd(p + 0, v.x);
  atomicAdd(p + 1, v.y);
  atomicAdd(p + 2, v.z);
  atomicAdd(p + 3, v.w);
}

// ---------------- per-column sum / sumsq (for BatchNorm) ----------------
__global__ void k_colstats(const float* __restrict__ h, float* __restrict__ stats,
                           int nrows, int rowsPerBlock) {
  int col = threadIdx.x & (DD - 1);
  int sub = threadIdx.x >> 7;          // 0..1
  int r0 = blockIdx.x * rowsPerBlock;
  int r1 = min(r0 + rowsPerBlock, nrows);
  float s = 0.f, q = 0.f;
  for (int r = r0 + sub; r < r1; r += 2) {
    float v = h[r * DD + col];
    s += v; q += v * v;
  }
  __shared__ float ls[256], lq[256];
  ls[threadIdx.x] = s; lq[threadIdx.x] = q;
  __syncthreads();
  if (sub == 0) {
    atomicAdd(&stats[col],      s + ls[threadIdx.x + 128]);
    atomicAdd(&stats[DD + col], q + lq[threadIdx.x + 128]);
  }
}

// ---------------- GEMM: out[nrows x 128] = f(in) @ W + b ----------------
// BN_IN: input transform relu((x - mu)*rsqrt(var+eps)*gamma + beta) folded into load
// RELU_OUT: relu on output
template<bool BN_IN, bool RELU_OUT>
__global__ __launch_bounds__(256) void k_gemm(
    const float* __restrict__ in, const float* __restrict__ W,
    const float* __restrict__ bias, float* __restrict__ out, int nrows,
    const float* __restrict__ stats, const float* __restrict__ gamma,
    const float* __restrict__ beta) {
  __shared__ float Ws[DD * DD];       // 64 KB
  __shared__ float scs[DD], shs[DD];
  int tid = threadIdx.x;
  {
    const float4* W4 = (const float4*)W;
    float4* Ws4 = (float4*)Ws;
#pragma unroll
    for (int i = 0; i < 16; i++) Ws4[tid + i * 256] = W4[tid + i * 256];
  }
  if (BN_IN && tid < DD) {
    float mu  = stats[tid] * (1.0f / NN);
    float var = stats[DD + tid] * (1.0f / NN) - mu * mu;
    float sc  = gamma[tid] * rsqrtf(var + BN_EPS_F);
    scs[tid] = sc;
    shs[tid] = beta[tid] - mu * sc;
  }
  __syncthreads();

  int lane8 = tid & 7;                       // col group 0..7
  int row0 = blockIdx.x * 64 + (tid >> 3);   // 32 rows, second set +32
  int row1 = row0 + 32;
  bool hasA = row0 < nrows, hasB = row1 < nrows;

  float4 acc0[4], acc1[4];
  const float4* b4 = (const float4*)bias;
#pragma unroll
  for (int j = 0; j < 4; j++) { acc0[j] = b4[lane8 + j * 8]; acc1[j] = acc0[j]; }

  const float4* Ws4 = (const float4*)Ws;
  const float4* inA = (const float4*)in + (size_t)row0 * 32;
  const float4* inB = (const float4*)in + (size_t)row1 * 32;

  for (int k0 = 0; k0 < 32; k0++) {
    float4 xa = hasA ? inA[k0] : make_float4(0.f, 0.f, 0.f, 0.f);
    float4 xb = hasB ? inB[k0] : make_float4(0.f, 0.f, 0.f, 0.f);
    float av[4] = {xa.x, xa.y, xa.z, xa.w};
    float bv[4] = {xb.x, xb.y, xb.z, xb.w};
#pragma unroll
    for (int k4 = 0; k4 < 4; k4++) {
      int k = k0 * 4 + k4;
      float a = av[k4], b = bv[k4];
      if (BN_IN) {
        float sc = scs[k], sh = shs[k];
        a = fmaxf(a * sc + sh, 0.f);
        b = fmaxf(b * sc + sh, 0.f);
      }
#pragma unroll
      for (int j = 0; j < 4; j++) {
        float4 w = Ws4[k * 32 + lane8 + j * 8];
        acc0[j].x += a * w.x; acc0[j].y += a * w.y; acc0[j].z += a * w.z; acc0[j].w += a * w.w;
        acc1[j].x += b * w.x; acc1[j].y += b * w.y; acc1[j].z += b * w.z; acc1[j].w += b * w.w;
      }
    }
  }
  if (RELU_OUT) {
#pragma unroll
    for (int j = 0; j < 4; j++) {
      acc0[j].x = fmaxf(acc0[j].x, 0.f); acc0[j].y = fmaxf(acc0[j].y, 0.f);
      acc0[j].z = fmaxf(acc0[j].z, 0.f); acc0[j].w = fmaxf(acc0[j].w, 0.f);
      acc1[j].x = fmaxf(acc1[j].x, 0.f); acc1[j].y = fmaxf(acc1[j].y, 0.f);
      acc1[j].z = fmaxf(acc1[j].z, 0.f); acc1[j].w = fmaxf(acc1[j].w, 0.f);
    }
  }
  if (hasA) {
    float4* o = (float4*)(out + (size_t)row0 * DD);
#pragma unroll
    for (int j = 0; j < 4; j++) o[lane8 + j * 8] = acc0[j];
  }
  if (hasB) {
    float4* o = (float4*)(out + (size_t)row1 * DD);
#pragma unroll
    for (int j = 0; j < 4; j++) o[lane8 + j * 8] = acc1[j];
  }
}

// ---------------- head: out = log_softmax(in @ Wl2 + bl2) ----------------
__global__ void k_head(const float* __restrict__ in, const float* __restrict__ W,
                       const float* __restrict__ b, float* __restrict__ out, int nrows) {
  int lane = threadIdx.x & 63;
  int row = blockIdx.x * 4 + (threadIdx.x >> 6);
  if (row >= nrows) return;
  const float* xr = in + (size_t)row * DD;
  float acc = 0.f;
  if (lane < DOUT) {
#pragma unroll 8
    for (int k = 0; k < DD; k++) acc += xr[k] * W[k * DOUT + lane];
    acc += b[lane];
  }
  float v = (lane < DOUT) ? acc : -INFINITY;
#pragma unroll
  for (int off = 32; off; off >>= 1) v = fmaxf(v, __shfl_xor(v, off));
  float e = (lane < DOUT) ? expf(acc - v) : 0.f;
#pragma unroll
  for (int off = 32; off; off >>= 1) e += __shfl_xor(e, off);
  if (lane < DOUT) out[(size_t)row * DOUT + lane] = acc - v - logf(e);
}

extern "C" void kernel_launch(void* const* d_in, const int* in_sizes, int n_in,
                              void* d_out, int out_size, void* d_ws, size_t ws_size,
                              hipStream_t stream) {
  const float* x   = (const float*)d_in[0];
  const int*   ei  = (const int*)d_in[1];
  const float* W1a = (const float*)d_in[2];
  const float* b1a = (const float*)d_in[3];
  const float* g1  = (const float*)d_in[4];
  const float* be1 = (const float*)d_in[5];
  const float* W2a = (const float*)d_in[6];
  const float* b2a = (const float*)d_in[7];
  const float* W1b = (const float*)d_in[8];
  const float* b1b = (const float*)d_in[9];
  const float* g2  = (const float*)d_in[10];
  const float* be2 = (const float*)d_in[11];
  const float* W2b = (const float*)d_in[12];
  const float* b2b = (const float*)d_in[13];
  const float* Wl1 = (const float*)d_in[14];
  const float* bl1 = (const float*)d_in[15];
  const float* Wl2 = (const float*)d_in[16];
  const float* bl2 = (const float*)d_in[17];
  float* out = (float*)d_out;

  float* bufA  = (float*)d_ws;
  float* bufB  = bufA + (size_t)NN * DD;
  float* stats = bufB + (size_t)NN * DD;

  const int* srcI = ei;
  const int* dstI = ei + NE;

  dim3 blk(256);
  int n4 = NN * 32;                      // float4 count of an N x 128 buffer
  int copyGrid = (n4 + 255) / 256;
  int scatGrid = (NE * 32 + 255) / 256;
  int gemmGrid = (NN + 63) / 64;

  // ---- conv1 ----
  k_copy<<<copyGrid, blk, 0, stream>>>((const float4*)x, (float4*)bufA, n4);
  k_scatter<<<scatGrid, blk, 0, stream>>>((const float4*)x, srcI, dstI, bufA);
  k_gemm<false, false><<<gemmGrid, blk, 0, stream>>>(bufA, W1a, b1a, bufB, NN,
                                                     nullptr, nullptr, nullptr);
  hipMemsetAsync(stats, 0, 2 * DD * sizeof(float), stream);
  k_colstats<<<250, blk, 0, stream>>>(bufB, stats, NN, 200);
  k_gemm<true, true><<<gemmGrid, blk, 0, stream>>>(bufB, W2a, b2a, bufA, NN,
                                                   stats, g1, be1);
  // ---- conv2 ----
  k_copy<<<copyGrid, blk, 0, stream>>>((const float4*)bufA, (float4*)bufB, n4);
  k_scatter<<<scatGrid, blk, 0, stream>>>((const float4*)bufA, srcI, dstI, bufB);
  k_gemm<false, false><<<gemmGrid, blk, 0, stream>>>(bufB, W1b, b1b, bufA, NN,
                                                     nullptr, nullptr, nullptr);
  hipMemsetAsync(stats, 0, 2 * DD * sizeof(float), stream);
  k_colstats<<<250, blk, 0, stream>>>(bufA, stats, NN, 200);
  k_gemm<true, true><<<gemmGrid, blk, 0, stream>>>(bufA, W2b, b2b, bufB, NN,
                                                   stats, g2, be2);
  // ---- head ----
  k_gemm<false, true><<<gemmGrid, blk, 0, stream>>>(bufB, Wl1, bl1, bufA, NN,
                                                    nullptr, nullptr, nullptr);
  k_head<<<(NN + 3) / 4, blk, 0, stream>>>(bufA, Wl2, bl2, out, NN);
}

// Round 2
// 613.339 us; speedup vs baseline: 5.0149x; 5.0149x over previous
//
#include <hip/hip_runtime.h>
#include <math.h>

#define NN 50000
#define NE 800000
#define DD 128
#define DOUT 40
#define BN_EPS_F 1e-5f

// ---------------- CSR build: degree histogram ----------------
__global__ void k_deg(const int* __restrict__ dstI, int* __restrict__ deg) {
  int e = blockIdx.x * 256 + threadIdx.x;
  if (e < NE) atomicAdd(&deg[dstI[e]], 1);
}

// ---------------- single-block exclusive scan of deg -> rowptr ----------------
__global__ __launch_bounds__(1024) void k_scan(const int* __restrict__ deg,
                                               int* __restrict__ rowptr) {
  __shared__ int warpsums[16];
  __shared__ int carry;
  if (threadIdx.x == 0) carry = 0;
  __syncthreads();
  for (int base = 0; base < NN; base += 1024) {
    int i = base + threadIdx.x;
    int v = (i < NN) ? deg[i] : 0;
    int lane = threadIdx.x & 63, w = threadIdx.x >> 6;
    int s = v;
#pragma unroll
    for (int off = 1; off < 64; off <<= 1) {
      int t = __shfl_up(s, off);
      if (lane >= off) s += t;
    }
    if (lane == 63) warpsums[w] = s;
    __syncthreads();
    int c = carry;
    if (threadIdx.x < 16) {
      int t = warpsums[threadIdx.x];
#pragma unroll
      for (int off = 1; off < 16; off <<= 1) {
        int u = __shfl_up(t, off);
        if (threadIdx.x >= off) t += u;
      }
      warpsums[threadIdx.x] = t;
    }
    __syncthreads();
    int woff = (w == 0) ? 0 : warpsums[w - 1];
    if (i < NN) rowptr[i] = c + woff + s - v;   // exclusive
    __syncthreads();
    if (threadIdx.x == 0) carry = c + warpsums[15];
    __syncthreads();
  }
  if (threadIdx.x == 0) rowptr[NN] = carry;     // == NE
}

// ---------------- CSR fill: csrc[slot(dst)] = src ----------------
__global__ void k_fill(const int* __restrict__ srcI, const int* __restrict__ dstI,
                       int* __restrict__ cursor, int* __restrict__ csrc) {
  int e = blockIdx.x * 256 + threadIdx.x;
  if (e >= NE) return;
  int p = atomicAdd(&cursor[dstI[e]], 1);
  csrc[p] = srcI[e];
}

// ---------------- gather aggregation: out[n] = x[n] + sum_j x[csrc[j]] ----------------
__global__ void k_aggr(const float4* __restrict__ x, const int* __restrict__ rowptr,
                       const int* __restrict__ csrc, float4* __restrict__ out) {
  int tid = blockIdx.x * 256 + threadIdx.x;
  int node = tid >> 5;
  if (node >= NN) return;
  int c = tid & 31;
  int b = rowptr[node], e = rowptr[node + 1];
  float4 acc = x[node * 32 + c];
  int j = b;
  for (; j + 1 < e; j += 2) {
    int s0 = csrc[j], s1 = csrc[j + 1];
    float4 v0 = x[s0 * 32 + c];
    float4 v1 = x[s1 * 32 + c];
    acc.x += v0.x; acc.y += v0.y; acc.z += v0.z; acc.w += v0.w;
    acc.x += v1.x; acc.y += v1.y; acc.z += v1.z; acc.w += v1.w;
  }
  if (j < e) {
    int s0 = csrc[j];
    float4 v0 = x[s0 * 32 + c];
    acc.x += v0.x; acc.y += v0.y; acc.z += v0.z; acc.w += v0.w;
  }
  out[node * 32 + c] = acc;
}

// ---------------- per-column sum / sumsq (for BatchNorm) ----------------
__global__ void k_colstats(const float* __restrict__ h, float* __restrict__ stats,
                           int nrows, int rowsPerBlock) {
  int col = threadIdx.x & (DD - 1);
  int sub = threadIdx.x >> 7;
  int r0 = blockIdx.x * rowsPerBlock;
  int r1 = min(r0 + rowsPerBlock, nrows);
  float s = 0.f, q = 0.f;
  for (int r = r0 + sub; r < r1; r += 2) {
    float v = h[r * DD + col];
    s += v; q += v * v;
  }
  __shared__ float ls[256], lq[256];
  ls[threadIdx.x] = s; lq[threadIdx.x] = q;
  __syncthreads();
  if (sub == 0) {
    atomicAdd(&stats[col],      s + ls[threadIdx.x + 128]);
    atomicAdd(&stats[DD + col], q + lq[threadIdx.x + 128]);
  }
}

// ---------------- GEMM: out[nrows x 128] = f(in) @ W + b ----------------
template<bool BN_IN, bool RELU_OUT>
__global__ __launch_bounds__(256) void k_gemm(
    const float* __restrict__ in, const float* __restrict__ W,
    const float* __restrict__ bias, float* __restrict__ out, int nrows,
    const float* __restrict__ stats, const float* __restrict__ gamma,
    const float* __restrict__ beta) {
  __shared__ float Ws[DD * DD];
  __shared__ float scs[DD], shs[DD];
  int tid = threadIdx.x;
  {
    const float4* W4 = (const float4*)W;
    float4* Ws4 = (float4*)Ws;
#pragma unroll
    for (int i = 0; i < 16; i++) Ws4[tid + i * 256] = W4[tid + i * 256];
  }
  if (BN_IN && tid < DD) {
    float mu  = stats[tid] * (1.0f / NN);
    float var = stats[DD + tid] * (1.0f / NN) - mu * mu;
    float sc  = gamma[tid] * rsqrtf(var + BN_EPS_F);
    scs[tid] = sc;
    shs[tid] = beta[tid] - mu * sc;
  }
  __syncthreads();

  int lane8 = tid & 7;
  int row0 = blockIdx.x * 64 + (tid >> 3);
  int row1 = row0 + 32;
  bool hasA = row0 < nrows, hasB = row1 < nrows;

  float4 acc0[4], acc1[4];
  const float4* b4 = (const float4*)bias;
#pragma unroll
  for (int j = 0; j < 4; j++) { acc0[j] = b4[lane8 + j * 8]; acc1[j] = acc0[j]; }

  const float4* Ws4 = (const float4*)Ws;
  const float4* inA = (const float4*)in + (size_t)row0 * 32;
  const float4* inB = (const float4*)in + (size_t)row1 * 32;

  for (int k0 = 0; k0 < 32; k0++) {
    float4 xa = hasA ? inA[k0] : make_float4(0.f, 0.f, 0.f, 0.f);
    float4 xb = hasB ? inB[k0] : make_float4(0.f, 0.f, 0.f, 0.f);
    float av[4] = {xa.x, xa.y, xa.z, xa.w};
    float bv[4] = {xb.x, xb.y, xb.z, xb.w};
#pragma unroll
    for (int k4 = 0; k4 < 4; k4++) {
      int k = k0 * 4 + k4;
      float a = av[k4], b = bv[k4];
      if (BN_IN) {
        float sc = scs[k], sh = shs[k];
        a = fmaxf(a * sc + sh, 0.f);
        b = fmaxf(b * sc + sh, 0.f);
      }
#pragma unroll
      for (int j = 0; j < 4; j++) {
        float4 w = Ws4[k * 32 + lane8 + j * 8];
        acc0[j].x += a * w.x; acc0[j].y += a * w.y; acc0[j].z += a * w.z; acc0[j].w += a * w.w;
        acc1[j].x += b * w.x; acc1[j].y += b * w.y; acc1[j].z += b * w.z; acc1[j].w += b * w.w;
      }
    }
  }
  if (RELU_OUT) {
#pragma unroll
    for (int j = 0; j < 4; j++) {
      acc0[j].x = fmaxf(acc0[j].x, 0.f); acc0[j].y = fmaxf(acc0[j].y, 0.f);
      acc0[j].z = fmaxf(acc0[j].z, 0.f); acc0[j].w = fmaxf(acc0[j].w, 0.f);
      acc1[j].x = fmaxf(acc1[j].x, 0.f); acc1[j].y = fmaxf(acc1[j].y, 0.f);
      acc1[j].z = fmaxf(acc1[j].z, 0.f); acc1[j].w = fmaxf(acc1[j].w, 0.f);
    }
  }
  if (hasA) {
    float4* o = (float4*)(out + (size_t)row0 * DD);
#pragma unroll
    for (int j = 0; j < 4; j++) o[lane8 + j * 8] = acc0[j];
  }
  if (hasB) {
    float4* o = (float4*)(out + (size_t)row1 * DD);
#pragma unroll
    for (int j = 0; j < 4; j++) o[lane8 + j * 8] = acc1[j];
  }
}

// ---------------- head: out = log_softmax(in @ Wl2 + bl2) ----------------
__global__ void k_head(const float* __restrict__ in, const float* __restrict__ W,
                       const float* __restrict__ b, float* __restrict__ out, int nrows) {
  int lane = threadIdx.x & 63;
  int row = blockIdx.x * 4 + (threadIdx.x >> 6);
  if (row >= nrows) return;
  const float* xr = in + (size_t)row * DD;
  float acc = 0.f;
  if (lane < DOUT) {
#pragma unroll 8
    for (int k = 0; k < DD; k++) acc += xr[k] * W[k * DOUT + lane];
    acc += b[lane];
  }
  float v = (lane < DOUT) ? acc : -INFINITY;
#pragma unroll
  for (int off = 32; off; off >>= 1) v = fmaxf(v, __shfl_xor(v, off));
  float e = (lane < DOUT) ? expf(acc - v) : 0.f;
#pragma unroll
  for (int off = 32; off; off >>= 1) e += __shfl_xor(e, off);
  if (lane < DOUT) out[(size_t)row * DOUT + lane] = acc - v - logf(e);
}

extern "C" void kernel_launch(void* const* d_in, const int* in_sizes, int n_in,
                              void* d_out, int out_size, void* d_ws, size_t ws_size,
                              hipStream_t stream) {
  const float* x   = (const float*)d_in[0];
  const int*   ei  = (const int*)d_in[1];
  const float* W1a = (const float*)d_in[2];
  const float* b1a = (const float*)d_in[3];
  const float* g1  = (const float*)d_in[4];
  const float* be1 = (const float*)d_in[5];
  const float* W2a = (const float*)d_in[6];
  const float* b2a = (const float*)d_in[7];
  const float* W1b = (const float*)d_in[8];
  const float* b1b = (const float*)d_in[9];
  const float* g2  = (const float*)d_in[10];
  const float* be2 = (const float*)d_in[11];
  const float* W2b = (const float*)d_in[12];
  const float* b2b = (const float*)d_in[13];
  const float* Wl1 = (const float*)d_in[14];
  const float* bl1 = (const float*)d_in[15];
  const float* Wl2 = (const float*)d_in[16];
  const float* bl2 = (const float*)d_in[17];
  float* out = (float*)d_out;

  float* bufA   = (float*)d_ws;                      // N x 128
  float* bufB   = bufA + (size_t)NN * DD;            // N x 128
  float* stats  = bufB + (size_t)NN * DD;            // 256
  int*   deg    = (int*)(stats + 2 * DD);            // N
  int*   rowptr = deg + NN;                          // N + 1
  int*   cursor = rowptr + NN + 1;                   // N
  int*   csrc   = cursor + NN;                       // E

  const int* srcI = ei;
  const int* dstI = ei + NE;

  dim3 blk(256);
  int edgeGrid = (NE + 255) / 256;
  int aggrGrid = (NN * 32 + 255) / 256;
  int gemmGrid = (NN + 63) / 64;

  // ---- CSR build (once; reused by both convs) ----
  hipMemsetAsync(deg, 0, NN * sizeof(int), stream);
  k_deg<<<edgeGrid, blk, 0, stream>>>(dstI, deg);
  k_scan<<<1, 1024, 0, stream>>>(deg, rowptr);
  hipMemcpyAsync(cursor, rowptr, NN * sizeof(int), hipMemcpyDeviceToDevice, stream);
  k_fill<<<edgeGrid, blk, 0, stream>>>(srcI, dstI, cursor, csrc);

  // ---- conv1 ----
  k_aggr<<<aggrGrid, blk, 0, stream>>>((const float4*)x, rowptr, csrc, (float4*)bufA);
  k_gemm<false, false><<<gemmGrid, blk, 0, stream>>>(bufA, W1a, b1a, bufB, NN,
                                                     nullptr, nullptr, nullptr);
  hipMemsetAsync(stats, 0, 2 * DD * sizeof(float), stream);
  k_colstats<<<250, blk, 0, stream>>>(bufB, stats, NN, 200);
  k_gemm<true, true><<<gemmGrid, blk, 0, stream>>>(bufB, W2a, b2a, bufA, NN,
                                                   stats, g1, be1);
  // ---- conv2 ----
  k_aggr<<<aggrGrid, blk, 0, stream>>>((const float4*)bufA, rowptr, csrc, (float4*)bufB);
  k_gemm<false, false><<<gemmGrid, blk, 0, stream>>>(bufB, W1b, b1b, bufA, NN,
                                                     nullptr, nullptr, nullptr);
  hipMemsetAsync(stats, 0, 2 * DD * sizeof(float), stream);
  k_colstats<<<250, blk, 0, stream>>>(bufA, stats, NN, 200);
  k_gemm<true, true><<<gemmGrid, blk, 0, stream>>>(bufA, W2b, b2b, bufB, NN,
                                                   stats, g2, be2);
  // ---- head ----
  k_gemm<false, true><<<gemmGrid, blk, 0, stream>>>(bufB, Wl1, bl1, bufA, NN,
                                                    nullptr, nullptr, nullptr);
  k_head<<<(NN + 3) / 4, blk, 0, stream>>>(bufA, Wl2, bl2, out, NN);
}